// Round 2
// baseline (2089.059 us; speedup 1.0000x reference)
//
#include <hip/hip_runtime.h>

#define NHD 32
#define SS  2048
#define HH  4096
#define H3  12288
#define HD  128

typedef __attribute__((ext_vector_type(4))) float f32x4;
typedef __attribute__((ext_vector_type(8))) short short8;

#define GLOAD_LDS16(gptr, lptr)                                                        \
  __builtin_amdgcn_global_load_lds((const __attribute__((address_space(1))) void*)(gptr), \
                                   (__attribute__((address_space(3))) void*)(lptr), 16, 0, 0)

__device__ __forceinline__ ushort f2bf(float f) {
  union { float f; unsigned u; } v; v.f = f;
  unsigned r = (v.u + 0x7FFFu + ((v.u >> 16) & 1u)) >> 16;
  return (ushort)r;
}
__device__ __forceinline__ float bf2f(ushort u) {
  union { unsigned u; float f; } v; v.u = ((unsigned)u) << 16;
  return v.f;
}

// ---------- fp32 -> bf16 convert (x4 vectorized) ----------
__global__ __launch_bounds__(256) void cvt_f32_bf16(const float* __restrict__ in,
                                                    ushort* __restrict__ out) {
  size_t i = ((size_t)blockIdx.x * 256 + threadIdx.x) * 4;
  float4 v = *(const float4*)(in + i);
  ushort4 r; r.x = f2bf(v.x); r.y = f2bf(v.y); r.z = f2bf(v.z); r.w = f2bf(v.w);
  *(ushort4*)(out + i) = r;
}

// ---------- transpose + convert: in fp32 [rows][cols] -> out bf16 [cols][rows] ----------
__global__ __launch_bounds__(256) void transpose_cvt(const float* __restrict__ in,
                                                     ushort* __restrict__ out,
                                                     int rows, int cols) {
  __shared__ float tile[32][33];
  int c0 = blockIdx.x * 32, r0 = blockIdx.y * 32;
  int tx = threadIdx.x, ty = threadIdx.y;
  #pragma unroll
  for (int i = ty; i < 32; i += 8)
    tile[i][tx] = in[(size_t)(r0 + i) * cols + (c0 + tx)];
  __syncthreads();
  #pragma unroll
  for (int i = ty; i < 32; i += 8)
    out[(size_t)(c0 + i) * rows + (r0 + tx)] = f2bf(tile[tx][i]);
}

// ---------- bf16 MFMA GEMM: C[M][N] = A[M][K] * BT[N][K]^T (+bias) ----------
// 128x128 tile, BK=64, 256 threads (4 waves), each wave 64x64 (4x4 frags of 16x16x32)
// m97 structure: global_load_lds width=16 staging, linear LDS, 2 barriers per K-step
template<bool BIAS, bool OUTBF16>
__global__ __launch_bounds__(256) void gemm_bf16(const ushort* __restrict__ A,
                                                 const ushort* __restrict__ BT,
                                                 const float* __restrict__ bias,
                                                 void* __restrict__ Cv,
                                                 int N, int K) {
  __shared__ __align__(16) ushort As[128 * 64];
  __shared__ __align__(16) ushort Bs[128 * 64];
  int tid  = threadIdx.x;
  int wave = tid >> 6, lane = tid & 63;
  int g = lane >> 4, q = lane & 15;
  int m0 = blockIdx.y * 128, n0 = blockIdx.x * 128;
  int wr = (wave >> 1) * 64, wc = (wave & 1) * 64;
  f32x4 acc[4][4] = {};
  for (int k0 = 0; k0 < K; k0 += 64) {
    __syncthreads();
    // stage via async global->LDS, 16B/lane, lane-contiguous LDS (wave base + lane*16)
    #pragma unroll
    for (int r = 0; r < 4; ++r) {
      int gr  = wave * 64 + 256 * r + lane;     // granule id (16B each), lane-contiguous
      int row = gr >> 3, col = (gr & 7) << 3;
      int ldsbase = (wave * 64 + 256 * r) * 8;  // wave-uniform LDS element offset
      GLOAD_LDS16(A  + (size_t)(m0 + row) * K + k0 + col, &As[ldsbase]);
      GLOAD_LDS16(BT + (size_t)(n0 + row) * K + k0 + col, &Bs[ldsbase]);
    }
    __syncthreads();
    #pragma unroll
    for (int kk = 0; kk < 64; kk += 32) {
      short8 af[4], bfr[4];
      #pragma unroll
      for (int m = 0; m < 4; ++m)
        af[m] = *(const short8*)(&As[(wr + m * 16 + q) * 64 + kk + 8 * g]);
      #pragma unroll
      for (int n = 0; n < 4; ++n)
        bfr[n] = *(const short8*)(&Bs[(wc + n * 16 + q) * 64 + kk + 8 * g]);
      #pragma unroll
      for (int m = 0; m < 4; ++m)
        #pragma unroll
        for (int n = 0; n < 4; ++n)
          acc[m][n] = __builtin_amdgcn_mfma_f32_16x16x32_bf16(af[m], bfr[n], acc[m][n], 0, 0, 0);
    }
  }
  #pragma unroll
  for (int m = 0; m < 4; ++m) {
    #pragma unroll
    for (int n = 0; n < 4; ++n) {
      int gcol = n0 + wc + n * 16 + q;
      float bv = 0.f;
      if (BIAS) bv = bias[gcol];
      #pragma unroll
      for (int r = 0; r < 4; ++r) {
        int grow = m0 + wr + m * 16 + g * 4 + r;   // C/D: col=l&15, row=(l>>4)*4+reg
        float v = acc[m][n][r] + bv;
        if (OUTBF16) ((ushort*)Cv)[(size_t)grow * N + gcol] = f2bf(v);
        else         ((float*) Cv)[(size_t)grow * N + gcol] = v;
      }
    }
  }
}

// ---------- RoPE (NeoX) + QKV split into head-major [b*NH+h][S][HD] bf16 ----------
__global__ __launch_bounds__(256) void rope_split(const ushort* __restrict__ qkv,
                                                  const int* __restrict__ positions,
                                                  ushort* __restrict__ qb,
                                                  ushort* __restrict__ kb,
                                                  ushort* __restrict__ vb) {
  int id = blockIdx.x * 256 + threadIdx.x;  // (t, h, d) : t*2048 + h*64 + d
  int d = id & 63;
  int h = (id >> 6) & 31;
  int t = id >> 11;                          // token 0..4095
  int b = t >> 11, s = t & 2047;
  float pos = (float)positions[t];
  // inv_freq = theta^(-d/64) = exp(-d * ln(10000)/64)
  float ang = pos * __expf(-(float)d * 0.14391156831212787f);
  float sv, cv;
  sincosf(ang, &sv, &cv);
  size_t src = (size_t)t * H3 + h * 128 + d;
  float q1 = bf2f(qkv[src]),        q2 = bf2f(qkv[src + 64]);
  float k1 = bf2f(qkv[src + 4096]), k2 = bf2f(qkv[src + 4160]);
  size_t dst = ((size_t)(b * NHD + h) * SS + s) * HD + d;
  qb[dst]      = f2bf(q1 * cv - q2 * sv);
  qb[dst + 64] = f2bf(q2 * cv + q1 * sv);
  kb[dst]      = f2bf(k1 * cv - k2 * sv);
  kb[dst + 64] = f2bf(k2 * cv + k1 * sv);
  vb[dst]      = qkv[src + 8192];
  vb[dst + 64] = qkv[src + 8256];
}

// ---------- causal flash attention ----------
// block = 256 thr (4 waves), per block: one (b,h), 64 q-rows (16 per wave), KV tiles of 32
__global__ __launch_bounds__(256) void attn_fwd(const ushort* __restrict__ qb,
                                                const ushort* __restrict__ kb,
                                                const ushort* __restrict__ vb,
                                                ushort* __restrict__ aout) {
  __shared__ __align__(16) ushort Ks[32 * 136];   // [kv 32][d 128 pad 136]
  __shared__ __align__(16) ushort Vt[128 * 40];   // [d 128][kv 32 pad 40]
  __shared__ __align__(16) ushort Pw[4 * 16 * 40];// per-wave [q 16][kv 32 pad 40]
  const float SCALE = 0.08838834764831845f;       // 1/sqrt(128)
  int tid = threadIdx.x, wave = tid >> 6, lane = tid & 63;
  int g = lane >> 4, q = lane & 15;
  int bh = blockIdx.y;
  int qb0 = blockIdx.x * 64;
  const ushort* Kh = kb + (size_t)bh * SS * HD;
  const ushort* Vh = vb + (size_t)bh * SS * HD;
  const ushort* Qh = qb + (size_t)bh * SS * HD;

  short8 qf[4];
  int qrow = qb0 + wave * 16 + q;                 // A-frag row = l&15
  #pragma unroll
  for (int c = 0; c < 4; ++c)
    qf[c] = *(const short8*)(Qh + (size_t)qrow * HD + c * 32 + 8 * g);

  f32x4 o[8] = {};
  float mrow[4] = {-1e30f, -1e30f, -1e30f, -1e30f};
  float lrow[4] = {0.f, 0.f, 0.f, 0.f};

  int nt = qb0 / 32 + 2;
  for (int kt = 0; kt < nt; ++kt) {
    int kv0 = kt * 32;
    __syncthreads();
    // stage K tile [32][128] -> Ks (padded rows)
    #pragma unroll
    for (int r = 0; r < 2; ++r) {
      int gr = tid + 256 * r;                     // 512 granules of 16B
      int row = gr >> 4, col = (gr & 15) << 3;
      *(uint4*)(&Ks[row * 136 + col]) =
          *(const uint4*)(Kh + (size_t)(kv0 + row) * HD + col);
    }
    // stage V transposed: Vt[d][kv]
    #pragma unroll
    for (int r = 0; r < 2; ++r) {
      int gr = tid + 256 * r;
      int row = gr >> 4, col = (gr & 15) << 3;
      uint4 v = *(const uint4*)(Vh + (size_t)(kv0 + row) * HD + col);
      ushort* pv = (ushort*)&v;
      #pragma unroll
      for (int i = 0; i < 8; ++i) Vt[(col + i) * 40 + row] = pv[i];
    }
    __syncthreads();

    // QK^T : S[16 q][32 kv]
    f32x4 sf[2] = {};
    #pragma unroll
    for (int c = 0; c < 4; ++c) {
      #pragma unroll
      for (int n = 0; n < 2; ++n) {
        short8 kf = *(const short8*)(&Ks[(n * 16 + q) * 136 + c * 32 + 8 * g]);
        sf[n] = __builtin_amdgcn_mfma_f32_16x16x32_bf16(qf[c], kf, sf[n], 0, 0, 0);
      }
    }

    // online softmax (rows live in reg r; 16 lanes of a group share 4 rows)
    float corr[4];
    #pragma unroll
    for (int r = 0; r < 4; ++r) {
      int grow = qb0 + wave * 16 + g * 4 + r;
      float s0 = sf[0][r] * SCALE;
      float s1 = sf[1][r] * SCALE;
      if (kv0 + q > grow)      s0 = -1e30f;
      if (kv0 + 16 + q > grow) s1 = -1e30f;
      float mx = fmaxf(s0, s1);
      #pragma unroll
      for (int off = 8; off; off >>= 1) mx = fmaxf(mx, __shfl_xor(mx, off));
      float mnew = fmaxf(mrow[r], mx);
      corr[r] = __expf(mrow[r] - mnew);
      mrow[r] = mnew;
      float p0 = __expf(s0 - mnew);
      float p1 = __expf(s1 - mnew);
      float rs = p0 + p1;
      #pragma unroll
      for (int off = 8; off; off >>= 1) rs += __shfl_xor(rs, off);
      lrow[r] = lrow[r] * corr[r] + rs;
      Pw[wave * 640 + (g * 4 + r) * 40 + q]      = f2bf(p0);
      Pw[wave * 640 + (g * 4 + r) * 40 + 16 + q] = f2bf(p1);
    }
    #pragma unroll
    for (int d0 = 0; d0 < 8; ++d0)
      #pragma unroll
      for (int r = 0; r < 4; ++r) o[d0][r] *= corr[r];

    // PV : O += P[16][32] * V[32][128]
    short8 pf = *(const short8*)(&Pw[wave * 640 + q * 40 + 8 * g]);
    #pragma unroll
    for (int d0 = 0; d0 < 8; ++d0) {
      short8 vf = *(const short8*)(&Vt[(d0 * 16 + q) * 40 + 8 * g]);
      o[d0] = __builtin_amdgcn_mfma_f32_16x16x32_bf16(pf, vf, o[d0], 0, 0, 0);
    }
  }

  // epilogue: aout[b, s, h*128 + d]
  int b = bh >> 5, h = bh & 31;
  #pragma unroll
  for (int r = 0; r < 4; ++r) {
    float inv = 1.0f / lrow[r];
    int srow = qb0 + wave * 16 + g * 4 + r;
    size_t base = ((size_t)(b * SS + srow)) * HH + h * 128;
    #pragma unroll
    for (int d0 = 0; d0 < 8; ++d0)
      aout[base + d0 * 16 + q] = f2bf(o[d0][r] * inv);
  }
}

extern "C" void kernel_launch(void* const* d_in, const int* in_sizes, int n_in,
                              void* d_out, int out_size, void* d_ws, size_t ws_size,
                              hipStream_t stream) {
  const int*   positions = (const int*)  d_in[0];
  const float* hidden    = (const float*)d_in[1];
  const float* w_qkv     = (const float*)d_in[2];
  const float* b_qkv     = (const float*)d_in[3];
  const float* w_proj    = (const float*)d_in[4];
  float* out = (float*)d_out;

  char* ws = (char*)d_ws;
  // layout (bytes): hsb 32M | wqkvT 96M | wpT 32M | qkvb 96M | q 32M | k 32M | v 32M
  ushort* hsb   = (ushort*)(ws);
  ushort* wqkvT = (ushort*)(ws + 0x02000000ULL);
  ushort* wpT   = (ushort*)(ws + 0x08000000ULL);
  ushort* qkvb  = (ushort*)(ws + 0x0A000000ULL);
  ushort* qbuf  = (ushort*)(ws + 0x10000000ULL);
  ushort* kbuf  = (ushort*)(ws + 0x12000000ULL);
  ushort* vbuf  = (ushort*)(ws + 0x14000000ULL);
  ushort* aout  = hsb;  // hidden-bf16 dead after QKV GEMM; reuse for attn output

  // 1) conversions
  cvt_f32_bf16<<<16384, 256, 0, stream>>>(hidden, hsb);                       // 16.7M elems
  transpose_cvt<<<dim3(384, 128), dim3(32, 8), 0, stream>>>(w_qkv, wqkvT, HH, H3);
  transpose_cvt<<<dim3(128, 128), dim3(32, 8), 0, stream>>>(w_proj, wpT, HH, HH);

  // 2) QKV GEMM: [4096][12288] = hsb[4096][4096] @ w_qkv + bias  (bf16 out)
  gemm_bf16<true, true><<<dim3(96, 32), 256, 0, stream>>>(hsb, wqkvT, b_qkv, qkvb, H3, HH);

  // 3) RoPE + split
  rope_split<<<32768, 256, 0, stream>>>(qkvb, positions, qbuf, kbuf, vbuf);

  // 4) causal flash attention
  attn_fwd<<<dim3(32, 64), 256, 0, stream>>>(qbuf, kbuf, vbuf, aout);

  // 5) output projection: fp32 out
  gemm_bf16<false, false><<<dim3(32, 32), 256, 0, stream>>>(aout, wpT, nullptr, out, HH, HH);
}

// Round 4
// 1744.027 us; speedup vs baseline: 1.1978x; 1.1978x over previous
//
#include <hip/hip_runtime.h>

#define NHD 32
#define SS  2048
#define HH  4096
#define H3  12288
#define HD  128

typedef __attribute__((ext_vector_type(4))) float f32x4;
typedef __attribute__((ext_vector_type(8))) short short8;

#define GLOAD_LDS16(gptr, lptr)                                                        \
  __builtin_amdgcn_global_load_lds((const __attribute__((address_space(1))) void*)(gptr), \
                                   (__attribute__((address_space(3))) void*)(lptr), 16, 0, 0)

__device__ __forceinline__ ushort f2bf(float f) {
  union { float f; unsigned u; } v; v.f = f;
  unsigned r = (v.u + 0x7FFFu + ((v.u >> 16) & 1u)) >> 16;
  return (ushort)r;
}
__device__ __forceinline__ float bf2f(ushort u) {
  union { unsigned u; float f; } v; v.u = ((unsigned)u) << 16;
  return v.f;
}

// ---------- fp32 -> bf16 convert ----------
__global__ __launch_bounds__(256) void cvt_f32_bf16(const float* __restrict__ in,
                                                    ushort* __restrict__ out) {
  size_t i = ((size_t)blockIdx.x * 256 + threadIdx.x) * 4;
  float4 v = *(const float4*)(in + i);
  ushort4 r; r.x = f2bf(v.x); r.y = f2bf(v.y); r.z = f2bf(v.z); r.w = f2bf(v.w);
  *(ushort4*)(out + i) = r;
}

// ---------- transpose + convert: fp32 [rows][cols] -> bf16 [cols][rows] ----------
__global__ __launch_bounds__(256) void transpose_cvt(const float* __restrict__ in,
                                                     ushort* __restrict__ out,
                                                     int rows, int cols) {
  __shared__ float tile[32][33];
  int c0 = blockIdx.x * 32, r0 = blockIdx.y * 32;
  int tx = threadIdx.x, ty = threadIdx.y;
  #pragma unroll
  for (int i = ty; i < 32; i += 8)
    tile[i][tx] = in[(size_t)(r0 + i) * cols + (c0 + tx)];
  __syncthreads();
  #pragma unroll
  for (int i = ty; i < 32; i += 8)
    out[(size_t)(c0 + i) * rows + (r0 + tx)] = f2bf(tile[tx][i]);
}

// ---------- V transpose: qkvb v-part [b,s][h*128+d] -> vt [bh][d][s] (bf16) ----------
__global__ __launch_bounds__(256) void vtrans(const ushort* __restrict__ qkvb,
                                              ushort* __restrict__ vt) {
  __shared__ ushort tile[32][33];
  int s0 = blockIdx.x * 32, d0 = blockIdx.y * 32, bh = blockIdx.z;
  int b = bh >> 5, h = bh & 31;
  int tx = threadIdx.x, ty = threadIdx.y;
  #pragma unroll
  for (int i = ty; i < 32; i += 8)
    tile[i][tx] = qkvb[(size_t)(b * SS + s0 + i) * H3 + 8192 + h * 128 + d0 + tx];
  __syncthreads();
  #pragma unroll
  for (int i = ty; i < 32; i += 8)
    vt[((size_t)bh * HD + d0 + i) * SS + s0 + tx] = tile[tx][i];
}

// ---------- bf16 MFMA GEMM (m97 structure) ----------
template<bool BIAS, bool OUTBF16>
__global__ __launch_bounds__(256) void gemm_bf16(const ushort* __restrict__ A,
                                                 const ushort* __restrict__ BT,
                                                 const float* __restrict__ bias,
                                                 void* __restrict__ Cv,
                                                 int N, int K) {
  __shared__ __align__(16) ushort As[128 * 64];
  __shared__ __align__(16) ushort Bs[128 * 64];
  int tid  = threadIdx.x;
  int wave = tid >> 6, lane = tid & 63;
  int g = lane >> 4, q = lane & 15;
  int m0 = blockIdx.y * 128, n0 = blockIdx.x * 128;
  int wr = (wave >> 1) * 64, wc = (wave & 1) * 64;
  f32x4 acc[4][4] = {};
  for (int k0 = 0; k0 < K; k0 += 64) {
    __syncthreads();
    #pragma unroll
    for (int r = 0; r < 4; ++r) {
      int gr  = wave * 64 + 256 * r + lane;
      int row = gr >> 3, col = (gr & 7) << 3;
      int ldsbase = (wave * 64 + 256 * r) * 8;
      GLOAD_LDS16(A  + (size_t)(m0 + row) * K + k0 + col, &As[ldsbase]);
      GLOAD_LDS16(BT + (size_t)(n0 + row) * K + k0 + col, &Bs[ldsbase]);
    }
    __syncthreads();
    #pragma unroll
    for (int kk = 0; kk < 64; kk += 32) {
      short8 af[4], bfr[4];
      #pragma unroll
      for (int m = 0; m < 4; ++m)
        af[m] = *(const short8*)(&As[(wr + m * 16 + q) * 64 + kk + 8 * g]);
      #pragma unroll
      for (int n = 0; n < 4; ++n)
        bfr[n] = *(const short8*)(&Bs[(wc + n * 16 + q) * 64 + kk + 8 * g]);
      #pragma unroll
      for (int m = 0; m < 4; ++m)
        #pragma unroll
        for (int n = 0; n < 4; ++n)
          acc[m][n] = __builtin_amdgcn_mfma_f32_16x16x32_bf16(af[m], bfr[n], acc[m][n], 0, 0, 0);
    }
  }
  #pragma unroll
  for (int m = 0; m < 4; ++m) {
    #pragma unroll
    for (int n = 0; n < 4; ++n) {
      int gcol = n0 + wc + n * 16 + q;
      float bv = 0.f;
      if (BIAS) bv = bias[gcol];
      #pragma unroll
      for (int r = 0; r < 4; ++r) {
        int grow = m0 + wr + m * 16 + g * 4 + r;
        float v = acc[m][n][r] + bv;
        if (OUTBF16) ((ushort*)Cv)[(size_t)grow * N + gcol] = f2bf(v);
        else         ((float*) Cv)[(size_t)grow * N + gcol] = v;
      }
    }
  }
}

// ---------- RoPE (NeoX) q,k only -> head-major [bh][s][d] bf16 ----------
__global__ __launch_bounds__(256) void rope_split(const ushort* __restrict__ qkv,
                                                  const int* __restrict__ positions,
                                                  ushort* __restrict__ qb,
                                                  ushort* __restrict__ kb) {
  int id = blockIdx.x * 256 + threadIdx.x;  // (t, h, d): t*2048 + h*64 + d
  int d = id & 63;
  int h = (id >> 6) & 31;
  int t = id >> 11;
  int b = t >> 11, s = t & 2047;
  float pos = (float)positions[t];
  float ang = pos * __expf(-(float)d * 0.14391156831212787f);
  float sv, cv;
  sincosf(ang, &sv, &cv);
  size_t src = (size_t)t * H3 + h * 128 + d;
  float q1 = bf2f(qkv[src]),        q2 = bf2f(qkv[src + 64]);
  float k1 = bf2f(qkv[src + 4096]), k2 = bf2f(qkv[src + 4160]);
  size_t dst = ((size_t)(b * NHD + h) * SS + s) * HD + d;
  qb[dst]      = f2bf(q1 * cv - q2 * sv);
  qb[dst + 64] = f2bf(q2 * cv + q1 * sv);
  kb[dst]      = f2bf(k1 * cv - k2 * sv);
  kb[dst + 64] = f2bf(k2 * cv + k1 * sv);
}

// ---------- causal flash attention v2 ----------
// 256 thr (4 waves). QBLK=128 (wave: 32 q-rows = 2 m-frags), KVBLK=64.
// K staged [64][256B] + V^T staged [128][128B], both XOR-swizzled (both-sides pattern:
// linear global_load_lds dest + inverse-swizzled global source col + swizzled ds_read).
__global__ __launch_bounds__(256) void attn_fwd(const ushort* __restrict__ qb,
                                                const ushort* __restrict__ kb,
                                                const ushort* __restrict__ vt,
                                                ushort* __restrict__ aout) {
  __shared__ __align__(16) ushort Ks[64 * 128];   // [kv 64][d 128], 256B rows, swizzled
  __shared__ __align__(16) ushort Vs[128 * 64];   // [d 128][kv 64], 128B rows, swizzled
  __shared__ __align__(16) ushort Pw[4 * 32 * 68];// per-wave [q 32][kv 64 pad 68]
  const float SCALE = 0.08838834764831845f;       // 1/sqrt(128)
  int tid = threadIdx.x, wave = tid >> 6, lane = tid & 63;
  int g = lane >> 4, q = lane & 15;
  int swk = (q & 7) << 4;                         // read-side swizzle (bytes)
  int bh = blockIdx.y;
  int qb0 = blockIdx.x * 128;
  const ushort* Qh = qb + (size_t)bh * SS * HD;
  const ushort* Kh = kb + (size_t)bh * SS * HD;
  const ushort* Vh = vt + (size_t)bh * SS * HD;   // [d][s]
  ushort* Pm = &Pw[wave * 32 * 68];

  // Q fragments in registers: 2 m-frags x 4 k-frags
  short8 qf[2][4];
  #pragma unroll
  for (int m = 0; m < 2; ++m)
    #pragma unroll
    for (int c = 0; c < 4; ++c)
      qf[m][c] = *(const short8*)(Qh + (size_t)(qb0 + wave * 32 + m * 16 + q) * HD + c * 32 + 8 * g);

  f32x4 o[2][8] = {};
  float mrow[2][4], lrow[2][4];
  #pragma unroll
  for (int m = 0; m < 2; ++m)
    #pragma unroll
    for (int r = 0; r < 4; ++r) { mrow[m][r] = -1e30f; lrow[m][r] = 0.f; }

  int nt = (qb0 >> 6) + 2;
  for (int kt = 0; kt < nt; ++kt) {
    int kv0 = kt * 64;
    __syncthreads();
    // stage K [64 rows x 256B], 1024 granules, inverse-swizzled source col
    #pragma unroll
    for (int r = 0; r < 4; ++r) {
      int gi  = r * 256 + tid;
      int row = gi >> 4, xb = (gi & 15) << 4;
      int src = xb ^ ((row & 7) << 4);
      GLOAD_LDS16(Kh + (size_t)(kv0 + row) * HD + (src >> 1),
                  &Ks[(r * 256 + wave * 64) * 8]);
    }
    // stage V^T [128 rows x 128B], 1024 granules
    #pragma unroll
    for (int r = 0; r < 4; ++r) {
      int gi  = r * 256 + tid;
      int row = gi >> 3, xb = (gi & 7) << 4;
      int src = xb ^ ((row & 7) << 4);
      GLOAD_LDS16(Vh + (size_t)row * SS + kv0 + (src >> 1),
                  &Vs[(r * 256 + wave * 64) * 8]);
    }
    __syncthreads();

    // QK^T: S[32 q][64 kv] per wave
    f32x4 sf[2][4] = {};
    #pragma unroll
    for (int c = 0; c < 4; ++c) {
      #pragma unroll
      for (int n = 0; n < 4; ++n) {
        int row = n * 16 + q;
        short8 kf = *(const short8*)(&Ks[row * 128 + (((c * 64 + 16 * g) ^ swk) >> 1)]);
        #pragma unroll
        for (int m = 0; m < 2; ++m)
          sf[m][n] = __builtin_amdgcn_mfma_f32_16x16x32_bf16(qf[m][c], kf, sf[m][n], 0, 0, 0);
      }
    }

    // online softmax (8 rows/lane: 2 m x 4 r; kv split as 4 n in-lane x 16 q-lanes)
    bool masked = (kt >= nt - 2);
    float corr[2][4];
    #pragma unroll
    for (int m = 0; m < 2; ++m) {
      #pragma unroll
      for (int r = 0; r < 4; ++r) {
        int qrow = qb0 + wave * 32 + m * 16 + g * 4 + r;
        float x[4];
        #pragma unroll
        for (int n = 0; n < 4; ++n) {
          x[n] = sf[m][n][r] * SCALE;
          if (masked && (kv0 + n * 16 + q > qrow)) x[n] = -1e30f;
        }
        float mx = fmaxf(fmaxf(x[0], x[1]), fmaxf(x[2], x[3]));
        #pragma unroll
        for (int off = 8; off; off >>= 1) mx = fmaxf(mx, __shfl_xor(mx, off));
        float mnew = fmaxf(mrow[m][r], mx);
        corr[m][r] = __expf(mrow[m][r] - mnew);
        mrow[m][r] = mnew;
        float rs = 0.f;
        #pragma unroll
        for (int n = 0; n < 4; ++n) {
          float p = __expf(x[n] - mnew);
          rs += p;
          Pm[(m * 16 + g * 4 + r) * 68 + n * 16 + q] = f2bf(p);
        }
        #pragma unroll
        for (int off = 8; off; off >>= 1) rs += __shfl_xor(rs, off);
        lrow[m][r] = lrow[m][r] * corr[m][r] + rs;
      }
    }
    // rescale O
    #pragma unroll
    for (int m = 0; m < 2; ++m)
      #pragma unroll
      for (int d0 = 0; d0 < 8; ++d0)
        #pragma unroll
        for (int r = 0; r < 4; ++r) o[m][d0][r] *= corr[m][r];

    // PV: O[32 q][128 d] += P[32 q][64 kv] x V[64 kv][128 d]
    short8 pf[2][2];
    #pragma unroll
    for (int m = 0; m < 2; ++m)
      #pragma unroll
      for (int c2 = 0; c2 < 2; ++c2)
        pf[m][c2] = *(const short8*)(&Pm[(m * 16 + q) * 68 + c2 * 32 + 8 * g]);
    #pragma unroll
    for (int d0 = 0; d0 < 8; ++d0) {
      int vrow = d0 * 16 + q;
      short8 vf0 = *(const short8*)(&Vs[vrow * 64 + (((16 * g) ^ swk) >> 1)]);
      short8 vf1 = *(const short8*)(&Vs[vrow * 64 + (((64 + 16 * g) ^ swk) >> 1)]);
      #pragma unroll
      for (int m = 0; m < 2; ++m) {
        o[m][d0] = __builtin_amdgcn_mfma_f32_16x16x32_bf16(pf[m][0], vf0, o[m][d0], 0, 0, 0);
        o[m][d0] = __builtin_amdgcn_mfma_f32_16x16x32_bf16(pf[m][1], vf1, o[m][d0], 0, 0, 0);
      }
    }
  }

  // epilogue: aout[b, s, h*128 + d]
  int b = bh >> 5, h = bh & 31;
  #pragma unroll
  for (int m = 0; m < 2; ++m) {
    #pragma unroll
    for (int r = 0; r < 4; ++r) {
      float inv = 1.0f / lrow[m][r];
      int srow = qb0 + wave * 32 + m * 16 + g * 4 + r;
      size_t base = ((size_t)(b * SS + srow)) * HH + h * 128;
      #pragma unroll
      for (int d0 = 0; d0 < 8; ++d0)
        aout[base + d0 * 16 + q] = f2bf(o[m][d0][r] * inv);
    }
  }
}

extern "C" void kernel_launch(void* const* d_in, const int* in_sizes, int n_in,
                              void* d_out, int out_size, void* d_ws, size_t ws_size,
                              hipStream_t stream) {
  const int*   positions = (const int*)  d_in[0];
  const float* hidden    = (const float*)d_in[1];
  const float* w_qkv     = (const float*)d_in[2];
  const float* b_qkv     = (const float*)d_in[3];
  const float* w_proj    = (const float*)d_in[4];
  float* out = (float*)d_out;

  char* ws = (char*)d_ws;
  ushort* hsb   = (ushort*)(ws);
  ushort* wqkvT = (ushort*)(ws + 0x02000000ULL);
  ushort* wpT   = (ushort*)(ws + 0x08000000ULL);
  ushort* qkvb  = (ushort*)(ws + 0x0A000000ULL);
  ushort* qbuf  = (ushort*)(ws + 0x10000000ULL);
  ushort* kbuf  = (ushort*)(ws + 0x12000000ULL);
  ushort* vtb   = (ushort*)(ws + 0x14000000ULL);  // V^T [bh][d][s]
  ushort* aout  = hsb;  // hidden-bf16 dead after QKV GEMM; reuse for attn output

  cvt_f32_bf16<<<16384, 256, 0, stream>>>(hidden, hsb);
  transpose_cvt<<<dim3(384, 128), dim3(32, 8), 0, stream>>>(w_qkv, wqkvT, HH, H3);
  transpose_cvt<<<dim3(128, 128), dim3(32, 8), 0, stream>>>(w_proj, wpT, HH, HH);

  gemm_bf16<true, true><<<dim3(96, 32), 256, 0, stream>>>(hsb, wqkvT, b_qkv, qkvb, H3, HH);

  rope_split<<<32768, 256, 0, stream>>>(qkvb, positions, qbuf, kbuf);
  vtrans<<<dim3(64, 4, 64), dim3(32, 8), 0, stream>>>(qkvb, vtb);

  attn_fwd<<<dim3(16, 64), 256, 0, stream>>>(qbuf, kbuf, vtb, aout);

  gemm_bf16<false, false><<<dim3(32, 32), 256, 0, stream>>>(aout, wpT, nullptr, out, HH, HH);
}